// Round 8
// baseline (637.899 us; speedup 1.0000x reference)
//
#include <hip/hip_runtime.h>

#define T_STEPS 4
#define BATCH   8
#define C_IN    64
#define C_OUT   64
#define HH      128
#define WW      128
#define TH      8
#define TW      16

// f32 rounding of math.exp(-0.5)
#define DECAY_F32 0.6065306597126334f

// Weight re-layout: w[co][ci][ky][kx] -> wt[j][ci][co], j = ky*3+kx
__global__ void wt_build_kernel(const float* __restrict__ w, float* __restrict__ wt) {
    int tid = blockIdx.x * blockDim.x + threadIdx.x;
    if (tid >= 9 * C_IN * C_OUT) return;
    int co = tid & 63;
    int ci = (tid >> 6) & 63;
    int j  = tid >> 12;
    wt[tid] = w[(co * C_IN + ci) * 9 + j];
}

// Exact replica of the reference's f32 arithmetic (probe-verified variant A):
// per output: acc = seq FMA chain over (ky, kx, ci-innermost); cb = acc + bias;
// vt = v*DECAY (rounded) + cb (rounded); spike = vt > 1; soft reset.
// Padded taps contribute fmaf(0,w,acc)==acc exactly, so all 9 j's always run.
__global__ __launch_bounds__(256) void snn_exact_kernel(
    const float* __restrict__ x,    // [T,B,C_IN,H,W]
    const float* __restrict__ wt,   // [9][C_IN][C_OUT]
    const float* __restrict__ bias, // [C_OUT]
    float* __restrict__ out)        // [T,B,C_OUT,H,W]
{
    __shared__ __align__(16) float sx[C_IN][TH + 2][24]; // 61440 B, rows 96B (b128-aligned, 2-way max)
    __shared__ __align__(16) float sw[C_IN][C_OUT];      // 16384 B, one j-slab

    const int tid = threadIdx.x;
    const int pxg = tid & 31;
    const int cog = tid >> 5;
    const int ly  = pxg >> 2;
    const int lx0 = (pxg & 3) << 2;
    const int b   = blockIdx.z;
    const int gy0 = blockIdx.y * TH;
    const int gx0 = blockIdx.x * TW;

    float bv[8];
#pragma unroll
    for (int o = 0; o < 8; ++o) bv[o] = bias[cog * 8 + o];

    float v[4][8];
#pragma unroll
    for (int p = 0; p < 4; ++p)
#pragma unroll
        for (int o = 0; o < 8; ++o) v[p][o] = 0.0f;

#define STAGE_SW(J)                                                              \
    {                                                                            \
        const float4* ws = reinterpret_cast<const float4*>(wt + (J) * 4096);     \
        float4* wd = reinterpret_cast<float4*>(&sw[0][0]);                       \
        for (int e = tid; e < C_IN * C_OUT / 4; e += 256) wd[e] = ws[e];         \
    }

#define COMPUTE(KY, KX)                                                          \
    _Pragma("unroll 2")                                                          \
    for (int ci = 0; ci < C_IN; ++ci) {                                          \
        const float4 a = *reinterpret_cast<const float4*>(&sx[ci][ly + (KY)][lx0]); \
        float xw0, xw1, xw2, xw3;                                                \
        if ((KX) == 0) { xw0 = a.x; xw1 = a.y; xw2 = a.z; xw3 = a.w; }           \
        else {                                                                   \
            const float2 c = *reinterpret_cast<const float2*>(&sx[ci][ly + (KY)][lx0 + 4]); \
            if ((KX) == 1) { xw0 = a.y; xw1 = a.z; xw2 = a.w; xw3 = c.x; }       \
            else           { xw0 = a.z; xw1 = a.w; xw2 = c.x; xw3 = c.y; }       \
        }                                                                        \
        const float4 w0 = *reinterpret_cast<const float4*>(&sw[ci][cog * 8]);    \
        const float4 w1 = *reinterpret_cast<const float4*>(&sw[ci][cog * 8 + 4]);\
        const float wv[8] = {w0.x, w0.y, w0.z, w0.w, w1.x, w1.y, w1.z, w1.w};    \
        const float xwv[4] = {xw0, xw1, xw2, xw3};                               \
        _Pragma("unroll")                                                        \
        for (int p = 0; p < 4; ++p)                                              \
            _Pragma("unroll")                                                    \
            for (int o = 0; o < 8; ++o)                                          \
                acc[p][o] = fmaf(xwv[p], wv[o], acc[p][o]);                      \
    }

#define RESTAGE(JN)       \
    __syncthreads();      \
    STAGE_SW(JN);         \
    __syncthreads();

    for (int t = 0; t < T_STEPS; ++t) {
        __syncthreads();  // prior iteration's compute done before overwriting sx/sw

        // ---- stage x tile: 64 ci x 10 rows x 18 cols (halo, zero-padded) ----
        const float* xsrc = x + ((size_t)(t * BATCH + b) * C_IN) * (HH * WW);
        for (int e = tid; e < C_IN * (TH + 2) * 18; e += 256) {
            int ci  = e / ((TH + 2) * 18);
            int rem = e - ci * ((TH + 2) * 18);
            int row = rem / 18;
            int col = rem - row * 18;
            int gy  = gy0 + row - 1;
            int gx  = gx0 + col - 1;
            float val = 0.0f;
            if ((unsigned)gy < (unsigned)HH && (unsigned)gx < (unsigned)WW)
                val = xsrc[ci * (HH * WW) + gy * WW + gx];
            sx[ci][row][col] = val;
        }
        STAGE_SW(0);
        __syncthreads();

        float acc[4][8];
#pragma unroll
        for (int p = 0; p < 4; ++p)
#pragma unroll
            for (int o = 0; o < 8; ++o) acc[p][o] = 0.0f;

        COMPUTE(0, 0); RESTAGE(1);
        COMPUTE(0, 1); RESTAGE(2);
        COMPUTE(0, 2); RESTAGE(3);
        COMPUTE(1, 0); RESTAGE(4);
        COMPUTE(1, 1); RESTAGE(5);
        COMPUTE(1, 2); RESTAGE(6);
        COMPUTE(2, 0); RESTAGE(7);
        COMPUTE(2, 1); RESTAGE(8);
        COMPUTE(2, 2);

        // ---- LIF update (exact f32 op sequence) + spike store ----
        float* obase = out + ((size_t)(t * BATCH + b) * C_OUT + cog * 8) * (HH * WW)
                     + (gy0 + ly) * WW + gx0 + lx0;
#pragma unroll
        for (int o = 0; o < 8; ++o) {
            float sv[4];
#pragma unroll
            for (int p = 0; p < 4; ++p) {
                float cb = __fadd_rn(acc[p][o], bv[o]);                  // conv + bias
                float vt = __fadd_rn(__fmul_rn(v[p][o], DECAY_F32), cb); // v*DECAY + cb
                bool fire = vt > 1.0f;
                sv[p]   = fire ? 1.0f : 0.0f;
                v[p][o] = fire ? 0.0f : vt;                              // soft reset
            }
            float4 s4 = {sv[0], sv[1], sv[2], sv[3]};
            *reinterpret_cast<float4*>(obase + (size_t)o * (HH * WW)) = s4;
        }
    }
#undef COMPUTE
#undef RESTAGE
#undef STAGE_SW
}

extern "C" void kernel_launch(void* const* d_in, const int* in_sizes, int n_in,
                              void* d_out, int out_size, void* d_ws, size_t ws_size,
                              hipStream_t stream) {
    const float* x    = (const float*)d_in[0];
    const float* w    = (const float*)d_in[1];
    const float* bias = (const float*)d_in[2];
    float* out = (float*)d_out;
    float* wt  = (float*)d_ws;   // 9*64*64*4 = 147456 bytes

    hipLaunchKernelGGL(wt_build_kernel, dim3((9 * C_IN * C_OUT + 255) / 256), dim3(256), 0, stream, w, wt);
    hipLaunchKernelGGL(snn_exact_kernel, dim3(WW / TW, HH / TH, BATCH), dim3(256), 0, stream, x, wt, bias, out);
}